// Round 1
// baseline (8231.207 us; speedup 1.0000x reference)
//
#include <hip/hip_runtime.h>
#include <stdint.h>

#define FP8_MAX 448.0f
#define QEPS 1e-12f

typedef __attribute__((ext_vector_type(4))) float floatx4;
typedef __attribute__((ext_vector_type(16))) float floatx16;

typedef const __attribute__((address_space(1))) void* gas_p;
typedef __attribute__((address_space(3))) void* las_p;

__device__ __forceinline__ void gld_lds16(const uint8_t* g, uint8_t* l) {
    __builtin_amdgcn_global_load_lds((gas_p)(const void*)g, (las_p)(void*)l, 16, 0, 0);
}

// ---------------------------------------------------------------------------
// Quantize activations x [M][K] fp32 -> xq [M][K] fp8, sx [K/128][M] fp32.
// ---------------------------------------------------------------------------
__global__ __launch_bounds__(256) void k_quant_act(
    const float* __restrict__ x, uint8_t* __restrict__ xq,
    float* __restrict__ sx, int M, int K)
{
    const int wave = threadIdx.x >> 6, lane = threadIdx.x & 63;
    const int KB = K >> 7;
    long bi = (long)blockIdx.x * 4 + wave;
    const int m = (int)(bi / KB);
    const int kb = (int)(bi % KB);
    const float* p = x + (long)m * K + (long)kb * 128 + lane * 2;
    float2 v = *(const float2*)p;
    float amax = fmaxf(fabsf(v.x), fabsf(v.y));
    #pragma unroll
    for (int off = 32; off >= 1; off >>= 1)
        amax = fmaxf(amax, __shfl_xor(amax, off));
    float ac = fmaxf(amax, QEPS);
    float rs = FP8_MAX / ac;
    if (lane == 0) sx[(long)kb * M + m] = ac / FP8_MAX;
    unsigned pk = (unsigned)__builtin_amdgcn_cvt_pk_fp8_f32(v.x * rs, v.y * rs, 0, false);
    *(unsigned short*)(xq + (long)m * K + (long)kb * 128 + lane * 2) = (unsigned short)pk;
}

// ---------------------------------------------------------------------------
// Quantize weights w [K][N] fp32 (scale along K in blocks of 128) ->
// wqT [N][K] fp8 (transposed), sw [K/128][N] fp32.
// ---------------------------------------------------------------------------
__global__ __launch_bounds__(256) void k_quant_w(
    const float* __restrict__ w, uint8_t* __restrict__ wqT,
    float* __restrict__ sw, int K, int N)
{
    __shared__ float tile[128][65];
    __shared__ float red[256];
    __shared__ float rsx[64];
    const int t = threadIdx.x;
    const long n0 = (long)blockIdx.x * 64;
    const long k0 = (long)blockIdx.y * 128;
    const int n = t & 63, rb = t >> 6;
    float amax = 0.0f;
    #pragma unroll 4
    for (int r = rb; r < 128; r += 4) {
        float v = w[(k0 + r) * N + n0 + n];
        tile[r][n] = v;
        amax = fmaxf(amax, fabsf(v));
    }
    red[t] = amax;
    __syncthreads();
    if (t < 64) {
        float a = fmaxf(fmaxf(red[t], red[t + 64]), fmaxf(red[t + 128], red[t + 192]));
        float ac = fmaxf(a, QEPS);
        sw[(long)blockIdx.y * N + n0 + t] = ac / FP8_MAX;
        rsx[t] = FP8_MAX / ac;
    }
    __syncthreads();
    const int c = t & 7;
    for (int nn = t >> 3; nn < 64; nn += 32) {
        float rs = rsx[nn];
        unsigned dv[4];
        #pragma unroll
        for (int q = 0; q < 4; ++q) {
            int r = c * 16 + q * 4;
            int lo = __builtin_amdgcn_cvt_pk_fp8_f32(tile[r][nn] * rs, tile[r + 1][nn] * rs, 0, false);
            dv[q] = (unsigned)__builtin_amdgcn_cvt_pk_fp8_f32(tile[r + 2][nn] * rs, tile[r + 3][nn] * rs, lo, true);
        }
        *(uint4*)(wqT + (n0 + nn) * K + k0 + c * 16) = make_uint4(dv[0], dv[1], dv[2], dv[3]);
    }
}

__device__ __forceinline__ float gelu_f(float x) {
    float u2 = 1.5957691216057308f * x * fmaf(0.044715f, x * x, 1.0f);
    float e = __expf(-u2);
    return x * __builtin_amdgcn_rcpf(1.0f + e);
}

// ---------------------------------------------------------------------------
// Blockwise-fp8 GEMM, 256x256 tile, BK=128 (= one scale block), 8 waves,
// mfma_f32_32x32x16_fp8_fp8, 8-phase schedule (T3+T4+T5 from the CDNA4 guide):
//   per phase: {ds_read frag | 2x global_load_lds prefetch of tile kb+1}
//              raw s_barrier ; lgkmcnt(0) ; setprio(1) ; 8x MFMA ; setprio(0)
//              rescale part->master by sA[row]*sB[col] ; raw s_barrier
// vmcnt is drained ONLY at the per-tile __syncthreads boundary, by which time
// the prefetch (issued phases 0-3) is long complete -> latency fully hidden.
// LDS tiles double-buffered, 16B-chunk XOR swizzle (chunk p = g ^ (row&7)),
// applied on BOTH the staging global source and the ds_read_b64 side.
// ---------------------------------------------------------------------------
template <bool FUSE>
__global__ __launch_bounds__(512, 2) void k_gemm_fp8(
    const uint8_t* __restrict__ Aq, const float* __restrict__ sA,
    const uint8_t* __restrict__ Bq, const float* __restrict__ sB,
    const float* __restrict__ bias,
    float* __restrict__ outF,
    uint8_t* __restrict__ outQ, float* __restrict__ outS,
    int M, int N, int K)
{
    __shared__ uint8_t sm[135168];
    uint8_t* ldsA = sm;                      // 2 x 32 KiB: [buf][256 rows][128B swz]
    uint8_t* ldsB = sm + 65536;              // 2 x 32 KiB
    float* lds_sa = (float*)(sm + 131072);   // 2 x 256 f32
    float* lds_sb = (float*)(sm + 133120);   // 2 x 256 f32

    const int tid = threadIdx.x;
    const int wave = tid >> 6, lane = tid & 63;
    const int l31 = lane & 31;
    const int x7 = l31 & 7;
    const int lh = lane >> 5;
    const int kh8 = lh * 8;
    const int wm = wave >> 2, wn = wave & 3;

    // XCD-aware bijective swizzle (grid here is always a multiple of 8)
    int bid = blockIdx.x;
    const int nwg = gridDim.x;
    if ((nwg & 7) == 0) bid = (bid & 7) * (nwg >> 3) + (bid >> 3);
    const int nbx = N >> 8;
    const long m0 = (long)(bid / nbx) * 256;
    const long n0 = (long)(bid % nbx) * 256;
    const int KB = K >> 7;

    // staging: lane -> (row = wave*32 + t*8 + (lane>>3), chunk = lane&7),
    // fetch swizzled source chunk g = (lane&7) ^ (row&7); LDS dest is linear.
    const int srow = lane >> 3;
    const int g16 = ((lane & 7) ^ srow) * 16;
    const uint8_t* Ag = Aq + (m0 + wave * 32 + srow) * K + g16;
    const uint8_t* Bg = Bq + (n0 + wave * 32 + srow) * K + g16;
    const int ldst = wave * 4096;

    // fragment LDS row bases (bytes); (row&7) == l31&7 for all mi/ni
    const int arow = (wm * 128 + l31) * 128;
    const int brow = (wn * 64 + l31) * 128;

    const floatx16 z16 = {0.f,0.f,0.f,0.f,0.f,0.f,0.f,0.f,
                          0.f,0.f,0.f,0.f,0.f,0.f,0.f,0.f};
    floatx16 master[4][2];
    #pragma unroll
    for (int mi = 0; mi < 4; ++mi) {
        master[mi][0] = z16;
        master[mi][1] = z16;
    }

    // prologue: stage tile 0 (+scales) into buf 0
    #pragma unroll
    for (int t = 0; t < 4; ++t) {
        gld_lds16(Ag + (long)(t * 8) * K, ldsA + ldst + t * 1024);
        gld_lds16(Bg + (long)(t * 8) * K, ldsB + ldst + t * 1024);
    }
    if (wave == 0)
        gld_lds16((const uint8_t*)(sA + m0) + lane * 16, (uint8_t*)lds_sa);
    else if (wave == 1)
        gld_lds16((const uint8_t*)(sB + n0) + lane * 16, (uint8_t*)lds_sb);
    __syncthreads();

    for (int kb = 0; kb < KB; ++kb) {
        const int cur = kb & 1, nb = cur ^ 1;
        const uint8_t* At = ldsA + cur * 32768;
        const uint8_t* Bt = ldsB + cur * 32768;
        const float* sac = lds_sa + cur * 256;
        const float* sbc = lds_sb + cur * 256;
        const bool pf = (kb + 1 < KB);
        const long kgo = (long)(kb + 1) * 128;
        long bf[2][8];

        #pragma unroll
        for (int mi = 0; mi < 4; ++mi) {
            // ds-load A fragments for this phase pair (mi, ni=0/1)
            long af[8];
            {
                const uint8_t* ar = At + arow + mi * 4096 + kh8;
                #pragma unroll
                for (int ks = 0; ks < 8; ++ks)
                    af[ks] = *(const long*)(ar + ((ks ^ x7) * 16));
            }
            floatx16 sav;
            #pragma unroll
            for (int ni = 0; ni < 2; ++ni) {
                const int p = mi * 2 + ni;
                if (p < 2) {  // B fragments, read once per tile, kept in regs
                    const uint8_t* br = Bt + brow + ni * 4096 + kh8;
                    #pragma unroll
                    for (int ks = 0; ks < 8; ++ks)
                        bf[ni][ks] = *(const long*)(br + ((ks ^ x7) * 16));
                }
                if (pf) {  // prefetch next tile: 2 issues/phase over phases 0-3
                    if (p == 0) {
                        gld_lds16(Ag + kgo, ldsA + nb * 32768 + ldst);
                        gld_lds16(Ag + kgo + (long)8 * K, ldsA + nb * 32768 + ldst + 1024);
                        if (wave == 0)
                            gld_lds16((const uint8_t*)(sA + (long)(kb + 1) * M + m0) + lane * 16,
                                      (uint8_t*)lds_sa + nb * 1024);
                        else if (wave == 1)
                            gld_lds16((const uint8_t*)(sB + (long)(kb + 1) * N + n0) + lane * 16,
                                      (uint8_t*)lds_sb + nb * 1024);
                    } else if (p == 1) {
                        gld_lds16(Ag + kgo + (long)16 * K, ldsA + nb * 32768 + ldst + 2048);
                        gld_lds16(Ag + kgo + (long)24 * K, ldsA + nb * 32768 + ldst + 3072);
                    } else if (p == 2) {
                        gld_lds16(Bg + kgo, ldsB + nb * 32768 + ldst);
                        gld_lds16(Bg + kgo + (long)8 * K, ldsB + nb * 32768 + ldst + 1024);
                    } else {
                        gld_lds16(Bg + kgo + (long)16 * K, ldsB + nb * 32768 + ldst + 2048);
                        gld_lds16(Bg + kgo + (long)24 * K, ldsB + nb * 32768 + ldst + 3072);
                    }
                }
                __builtin_amdgcn_s_barrier();
                asm volatile("s_waitcnt lgkmcnt(0)" ::: "memory");
                __builtin_amdgcn_s_setprio(1);
                floatx16 part = __builtin_amdgcn_mfma_f32_32x32x16_fp8_fp8(
                    af[0], bf[ni][0], z16, 0, 0, 0);
                #pragma unroll
                for (int ks = 1; ks < 8; ++ks)
                    part = __builtin_amdgcn_mfma_f32_32x32x16_fp8_fp8(
                        af[ks], bf[ni][ks], part, 0, 0, 0);
                __builtin_amdgcn_s_setprio(0);
                if (ni == 0) {
                    // per-row scales; C/D rows = (r&3)+8*(r>>2)+4*lh (+mi*32+wm*128)
                    const int sbase = wm * 128 + mi * 32 + 4 * lh;
                    float4 s0 = *(const float4*)&sac[sbase];
                    float4 s1 = *(const float4*)&sac[sbase + 8];
                    float4 s2 = *(const float4*)&sac[sbase + 16];
                    float4 s3 = *(const float4*)&sac[sbase + 24];
                    floatx16 t = {s0.x, s0.y, s0.z, s0.w, s1.x, s1.y, s1.z, s1.w,
                                  s2.x, s2.y, s2.z, s2.w, s3.x, s3.y, s3.z, s3.w};
                    sav = t;
                }
                const float sbv = sbc[wn * 64 + ni * 32 + l31];
                master[mi][ni] += (part * sav) * sbv;
                __builtin_amdgcn_s_barrier();
            }
        }
        __syncthreads();  // tile boundary: drains the (long-done) prefetch
    }

    const float bcol0 = bias[n0 + wn * 64 + l31];
    const float bcol1 = bias[n0 + wn * 64 + 32 + l31];

    if (FUSE) {
        float* rm = (float*)(sm + 65536);   // [4][256] per-wn row amax
        float* rs = (float*)(sm + 69632);   // [2][256] row rscale
        float rmax[4][16];
        #pragma unroll
        for (int mi = 0; mi < 4; ++mi)
            #pragma unroll
            for (int r = 0; r < 16; ++r) {
                float g0 = gelu_f(master[mi][0][r] + bcol0);
                float g1 = gelu_f(master[mi][1][r] + bcol1);
                master[mi][0][r] = g0;
                master[mi][1][r] = g1;
                rmax[mi][r] = fmaxf(fabsf(g0), fabsf(g1));
            }
        #pragma unroll
        for (int off = 1; off < 32; off <<= 1)
            #pragma unroll
            for (int mi = 0; mi < 4; ++mi)
                #pragma unroll
                for (int r = 0; r < 16; ++r)
                    rmax[mi][r] = fmaxf(rmax[mi][r], __shfl_xor(rmax[mi][r], off));
        if (l31 == 0) {
            #pragma unroll
            for (int mi = 0; mi < 4; ++mi)
                #pragma unroll
                for (int r = 0; r < 16; ++r)
                    rm[wn * 256 + wm * 128 + mi * 32 + (r & 3) + 8 * (r >> 2) + 4 * lh] = rmax[mi][r];
        }
        __syncthreads();
        if (tid < 256) {
            const float a0 = fmaxf(fmaxf(rm[tid], rm[256 + tid]), QEPS);
            const float a1 = fmaxf(fmaxf(rm[512 + tid], rm[768 + tid]), QEPS);
            outS[(n0 >> 7) * M + m0 + tid] = a0 / FP8_MAX;
            outS[((n0 >> 7) + 1) * M + m0 + tid] = a1 / FP8_MAX;
            rs[tid] = FP8_MAX / a0;
            rs[256 + tid] = FP8_MAX / a1;
        }
        __syncthreads();
        uint8_t* pack = sm;  // [256][256] bytes (tile bufs dead now)
        #pragma unroll
        for (int mi = 0; mi < 4; ++mi)
            #pragma unroll
            for (int r = 0; r < 16; ++r) {
                const int row = wm * 128 + mi * 32 + (r & 3) + 8 * (r >> 2) + 4 * lh;
                const float rsv = rs[(wn >> 1) * 256 + row];
                const unsigned b0 = (unsigned)__builtin_amdgcn_cvt_pk_fp8_f32(
                                        master[mi][0][r] * rsv, 0.f, 0, false) & 0xffu;
                const unsigned b1 = (unsigned)__builtin_amdgcn_cvt_pk_fp8_f32(
                                        master[mi][1][r] * rsv, 0.f, 0, false) & 0xffu;
                pack[row * 256 + wn * 64 + l31] = (uint8_t)b0;
                pack[row * 256 + wn * 64 + 32 + l31] = (uint8_t)b1;
            }
        __syncthreads();
        #pragma unroll
        for (int i = 0; i < 8; ++i) {
            const int ch = tid + i * 512;
            const int row = ch >> 4, coff = (ch & 15) * 16;
            *(uint4*)(outQ + (m0 + row) * N + n0 + coff) = *(const uint4*)(pack + ch * 16);
        }
    } else {
        #pragma unroll
        for (int mi = 0; mi < 4; ++mi)
            #pragma unroll
            for (int r = 0; r < 16; ++r) {
                const long grow = m0 + wm * 128 + mi * 32 + (r & 3) + 8 * (r >> 2) + 4 * lh;
                float* o = outF + grow * N + n0 + wn * 64 + l31;
                o[0] = master[mi][0][r] + bcol0;
                o[32] = master[mi][1][r] + bcol1;
            }
    }
}

extern "C" void kernel_launch(void* const* d_in, const int* in_sizes, int n_in,
                              void* d_out, int out_size, void* d_ws, size_t ws_size,
                              hipStream_t stream)
{
    (void)n_in; (void)out_size; (void)ws_size;
    const float* x  = (const float*)d_in[0];
    const float* w1 = (const float*)d_in[1];
    const float* b1 = (const float*)d_in[2];
    const float* w2 = (const float*)d_in[3];
    const float* b2 = (const float*)d_in[4];
    float* out = (float*)d_out;

    const int N1 = in_sizes[2];       // 8192
    const int K1 = in_sizes[1] / N1;  // 2048
    const int M  = in_sizes[0] / K1;  // 8192
    const int N2 = in_sizes[4];       // 8192
    const int K2 = in_sizes[3] / N2;  // 8192 (= N1)

    uint8_t* p = (uint8_t*)d_ws;
    uint8_t* xq  = p; p += (size_t)M * K1;
    uint8_t* w1q = p; p += (size_t)N1 * K1;
    uint8_t* hq  = p; p += (size_t)M * N1;
    uint8_t* w2q = p; p += (size_t)N2 * K2;
    float* sx  = (float*)p; p += (size_t)(K1 / 128) * M * 4;
    float* sw1 = (float*)p; p += (size_t)(K1 / 128) * N1 * 4;
    float* sh  = (float*)p; p += (size_t)(K2 / 128) * M * 4;
    float* sw2 = (float*)p; p += (size_t)(K2 / 128) * N2 * 4;

    k_quant_act<<<dim3(M * (K1 / 128) / 4), dim3(256), 0, stream>>>(x, xq, sx, M, K1);
    k_quant_w<<<dim3(N1 / 64, K1 / 128), dim3(256), 0, stream>>>(w1, w1q, sw1, K1, N1);
    k_quant_w<<<dim3(N2 / 64, K2 / 128), dim3(256), 0, stream>>>(w2, w2q, sw2, K2, N2);
    k_gemm_fp8<true><<<dim3((M / 256) * (N1 / 256)), dim3(512), 0, stream>>>(
        xq, sx, w1q, sw1, b1, (float*)nullptr, hq, sh, M, N1, K1);
    k_gemm_fp8<false><<<dim3((M / 256) * (N2 / 256)), dim3(512), 0, stream>>>(
        hq, sh, w2q, sw2, b2, out, (uint8_t*)nullptr, (float*)nullptr, M, N2, K2);
}